// Round 11
// baseline (5315.820 us; speedup 1.0000x reference)
//
#include <hip/hip_runtime.h>
#include <cstdint>
#include <cstddef>

#define T4096 4096
#define TM1 4095
#define NV 88
#define NH 512
#define NR 512
#define GS 20
#define EPSV 1e-6f
#define NCHUNK 512   // 8-row consumer chunks

// ws float offsets
#define U_OFF 0                         // 4095*512 floats
#define AB_OFF 2096640                  // A; rows re-used as published-U slots
#define SC_OFF 4553640                  // scalars + sync area
// u32 layout at sc: [0..2] accumulators, [8..15] xcd claim counts,
// [16] winner, [17..32] handshake words, [33..36] verdicts,
// [56] chunk queue counter (own line),
// [64 + i*16] progress flags, ONE PER 64B LINE (i = 0..7)

__device__ __forceinline__ unsigned int agent_load_u32(const unsigned int* p) {
  return __hip_atomic_load(p, __ATOMIC_RELAXED, __HIP_MEMORY_SCOPE_AGENT);
}
__device__ __forceinline__ void agent_store_f32(float* p, float v) {
  __hip_atomic_store(p, v, __ATOMIC_RELAXED, __HIP_MEMORY_SCOPE_AGENT);
}
__device__ __forceinline__ float sigmoidf_(float x) {
  return 1.0f / (1.0f + expf(-x));
}

// sc0 = SE-scope: bypasses L1, served by the XCD-shared L2.
__device__ __forceinline__ void store_sc0(float* p, float v) {
  asm volatile("global_store_dword %0, %1, off sc0" :: "v"(p), "v"(v) : "memory");
}
__device__ __forceinline__ unsigned load_sc0(const unsigned* p) {
  unsigned r;
  asm volatile("global_load_dword %0, %1, off sc0\n\ts_waitcnt vmcnt(0)"
               : "=v"(r) : "v"(p) : "memory");
  return r;
}
// System-scope (sc0 sc1): LLC-visible to all XCDs.
__device__ __forceinline__ void store_sys_u32(unsigned* p, unsigned v) {
  asm volatile("global_store_dword %0, %1, off sc0 sc1" :: "v"(p), "v"(v) : "memory");
}
__device__ __forceinline__ unsigned load_sys_u32(const unsigned* p) {
  unsigned r;
  asm volatile("global_load_dword %0, %1, off sc0 sc1\n\ts_waitcnt vmcnt(0)"
               : "=v"(r) : "v"(p) : "memory");
  return r;
}
// Paired 16B sys loads, single drain: staging reads 8 floats per thread.
__device__ __forceinline__ void load_sys_f32x4x2(const float* p, float4& a, float4& b) {
  asm volatile("global_load_dwordx4 %0, %2, off sc0 sc1\n\t"
               "global_load_dwordx4 %1, %3, off sc0 sc1\n\t"
               "s_waitcnt vmcnt(0)"
               : "=&v"(a), "=&v"(b)
               : "v"(p), "v"(p + 4) : "memory");
}

// No-drain rolling poll (R4-verified) -- PRODUCER blocks only (entry invariant:
// vmcnt drained by the preceding barrier).
__device__ __forceinline__ unsigned poll_nd_sc0(const unsigned* p,
                                                unsigned& s1, unsigned& s2,
                                                unsigned& s3, unsigned& s4) {
  unsigned rA;
  asm volatile(
    "v_mov_b32 %0, -1\n\t"
    "global_load_dword %1, %5, off sc0\n\t"
    "global_load_dword %2, %5, off sc0\n\t"
    "global_load_dword %3, %5, off sc0\n\t"
    "global_load_dword %4, %5, off sc0\n\t"
    "Lr%=:\n\t"
    "s_waitcnt vmcnt(3)\n\t"
    "v_cmp_ne_u32 vcc, -1, %1\n\t"
    "v_cndmask_b32 %0, %0, %1, vcc\n\t"
    "v_cmp_eq_u32 vcc, -1, %0\n\t"
    "s_cbranch_vccz Le%=\n\t"
    "global_load_dword %1, %5, off sc0\n\t"
    "s_waitcnt vmcnt(3)\n\t"
    "v_cmp_ne_u32 vcc, -1, %2\n\t"
    "v_cndmask_b32 %0, %0, %2, vcc\n\t"
    "v_cmp_eq_u32 vcc, -1, %0\n\t"
    "s_cbranch_vccz Le%=\n\t"
    "global_load_dword %2, %5, off sc0\n\t"
    "s_waitcnt vmcnt(3)\n\t"
    "v_cmp_ne_u32 vcc, -1, %3\n\t"
    "v_cndmask_b32 %0, %0, %3, vcc\n\t"
    "v_cmp_eq_u32 vcc, -1, %0\n\t"
    "s_cbranch_vccz Le%=\n\t"
    "global_load_dword %3, %5, off sc0\n\t"
    "s_waitcnt vmcnt(3)\n\t"
    "v_cmp_ne_u32 vcc, -1, %4\n\t"
    "v_cndmask_b32 %0, %0, %4, vcc\n\t"
    "v_cmp_eq_u32 vcc, -1, %0\n\t"
    "s_cbranch_vccz Le%=\n\t"
    "global_load_dword %4, %5, off sc0\n\t"
    "s_branch Lr%=\n\t"
    "Le%=:\n\t"
    : "=&v"(rA), "+v"(s1), "+v"(s2), "+v"(s3), "+v"(s4)
    : "v"(p) : "vcc", "memory");
  return rA;
}
__device__ __forceinline__ unsigned poll_nd_sys(const unsigned* p,
                                                unsigned& s1, unsigned& s2,
                                                unsigned& s3, unsigned& s4) {
  unsigned rA;
  asm volatile(
    "v_mov_b32 %0, -1\n\t"
    "global_load_dword %1, %5, off sc0 sc1\n\t"
    "global_load_dword %2, %5, off sc0 sc1\n\t"
    "global_load_dword %3, %5, off sc0 sc1\n\t"
    "global_load_dword %4, %5, off sc0 sc1\n\t"
    "Lq%=:\n\t"
    "s_waitcnt vmcnt(3)\n\t"
    "v_cmp_ne_u32 vcc, -1, %1\n\t"
    "v_cndmask_b32 %0, %0, %1, vcc\n\t"
    "v_cmp_eq_u32 vcc, -1, %0\n\t"
    "s_cbranch_vccz Lf%=\n\t"
    "global_load_dword %1, %5, off sc0 sc1\n\t"
    "s_waitcnt vmcnt(3)\n\t"
    "v_cmp_ne_u32 vcc, -1, %2\n\t"
    "v_cndmask_b32 %0, %0, %2, vcc\n\t"
    "v_cmp_eq_u32 vcc, -1, %0\n\t"
    "s_cbranch_vccz Lf%=\n\t"
    "global_load_dword %2, %5, off sc0 sc1\n\t"
    "s_waitcnt vmcnt(3)\n\t"
    "v_cmp_ne_u32 vcc, -1, %3\n\t"
    "v_cndmask_b32 %0, %0, %3, vcc\n\t"
    "v_cmp_eq_u32 vcc, -1, %0\n\t"
    "s_cbranch_vccz Lf%=\n\t"
    "global_load_dword %3, %5, off sc0 sc1\n\t"
    "s_waitcnt vmcnt(3)\n\t"
    "v_cmp_ne_u32 vcc, -1, %4\n\t"
    "v_cndmask_b32 %0, %0, %4, vcc\n\t"
    "v_cmp_eq_u32 vcc, -1, %0\n\t"
    "s_cbranch_vccz Lf%=\n\t"
    "global_load_dword %4, %5, off sc0 sc1\n\t"
    "s_branch Lq%=\n\t"
    "Lf%=:\n\t"
    : "=&v"(rA), "+v"(s1), "+v"(s2), "+v"(s3), "+v"(s4)
    : "v"(p) : "vcc", "memory");
  return rA;
}

// Entry/exit-drained rolling poll (R2-verified) -- REPUBLISHER block. The
// entry vmcnt(0) also drains its own in-flight sys stores, so stale loads
// never alias the reused registers (no barrier exists to do it for us).
__device__ __forceinline__ unsigned poll_rd_sc0(const unsigned* p) {
  unsigned rA, r0, r1, r2, r3;
  asm volatile(
    "s_waitcnt vmcnt(0)\n\t"
    "v_mov_b32 %0, -1\n\t"
    "global_load_dword %1, %5, off sc0\n\t"
    "global_load_dword %2, %5, off sc0\n\t"
    "global_load_dword %3, %5, off sc0\n\t"
    "global_load_dword %4, %5, off sc0\n\t"
    "Lr%=:\n\t"
    "s_waitcnt vmcnt(3)\n\t"
    "v_cmp_ne_u32 vcc, -1, %1\n\t"
    "v_cndmask_b32 %0, %0, %1, vcc\n\t"
    "v_cmp_eq_u32 vcc, -1, %0\n\t"
    "s_cbranch_vccz Le%=\n\t"
    "global_load_dword %1, %5, off sc0\n\t"
    "s_waitcnt vmcnt(3)\n\t"
    "v_cmp_ne_u32 vcc, -1, %2\n\t"
    "v_cndmask_b32 %0, %0, %2, vcc\n\t"
    "v_cmp_eq_u32 vcc, -1, %0\n\t"
    "s_cbranch_vccz Le%=\n\t"
    "global_load_dword %2, %5, off sc0\n\t"
    "s_waitcnt vmcnt(3)\n\t"
    "v_cmp_ne_u32 vcc, -1, %3\n\t"
    "v_cndmask_b32 %0, %0, %3, vcc\n\t"
    "v_cmp_eq_u32 vcc, -1, %0\n\t"
    "s_cbranch_vccz Le%=\n\t"
    "global_load_dword %3, %5, off sc0\n\t"
    "s_waitcnt vmcnt(3)\n\t"
    "v_cmp_ne_u32 vcc, -1, %4\n\t"
    "v_cndmask_b32 %0, %0, %4, vcc\n\t"
    "v_cmp_eq_u32 vcc, -1, %0\n\t"
    "s_cbranch_vccz Le%=\n\t"
    "global_load_dword %4, %5, off sc0\n\t"
    "s_branch Lr%=\n\t"
    "Le%=:\n\t"
    "s_waitcnt vmcnt(0)\n\t"
    : "=&v"(rA), "=&v"(r0), "=&v"(r1), "=&v"(r2), "=&v"(r3)
    : "v"(p) : "vcc", "memory");
  return rA;
}
__device__ __forceinline__ unsigned poll_rd_sys(const unsigned* p) {
  unsigned rA, r0, r1, r2, r3;
  asm volatile(
    "s_waitcnt vmcnt(0)\n\t"
    "v_mov_b32 %0, -1\n\t"
    "global_load_dword %1, %5, off sc0 sc1\n\t"
    "global_load_dword %2, %5, off sc0 sc1\n\t"
    "global_load_dword %3, %5, off sc0 sc1\n\t"
    "global_load_dword %4, %5, off sc0 sc1\n\t"
    "Lq%=:\n\t"
    "s_waitcnt vmcnt(3)\n\t"
    "v_cmp_ne_u32 vcc, -1, %1\n\t"
    "v_cndmask_b32 %0, %0, %1, vcc\n\t"
    "v_cmp_eq_u32 vcc, -1, %0\n\t"
    "s_cbranch_vccz Lf%=\n\t"
    "global_load_dword %1, %5, off sc0 sc1\n\t"
    "s_waitcnt vmcnt(3)\n\t"
    "v_cmp_ne_u32 vcc, -1, %2\n\t"
    "v_cndmask_b32 %0, %0, %2, vcc\n\t"
    "v_cmp_eq_u32 vcc, -1, %0\n\t"
    "s_cbranch_vccz Lf%=\n\t"
    "global_load_dword %2, %5, off sc0 sc1\n\t"
    "s_waitcnt vmcnt(3)\n\t"
    "v_cmp_ne_u32 vcc, -1, %3\n\t"
    "v_cndmask_b32 %0, %0, %3, vcc\n\t"
    "v_cmp_eq_u32 vcc, -1, %0\n\t"
    "s_cbranch_vccz Lf%=\n\t"
    "global_load_dword %3, %5, off sc0 sc1\n\t"
    "s_waitcnt vmcnt(3)\n\t"
    "v_cmp_ne_u32 vcc, -1, %4\n\t"
    "v_cndmask_b32 %0, %0, %4, vcc\n\t"
    "v_cmp_eq_u32 vcc, -1, %0\n\t"
    "s_cbranch_vccz Lf%=\n\t"
    "global_load_dword %4, %5, off sc0 sc1\n\t"
    "s_branch Lq%=\n\t"
    "Lf%=:\n\t"
    "s_waitcnt vmcnt(0)\n\t"
    : "=&v"(rA), "=&v"(r0), "=&v"(r1), "=&v"(r2), "=&v"(r3)
    : "v"(p) : "vcc", "memory");
  return rA;
}

// ---------------- K_A: A[t][r] = sum_v wvu[r][v]*v_seq[t][v] + bu[r] ----------------
__global__ __launch_bounds__(256) void k_a(const float* __restrict__ visible,
                                           const float* __restrict__ wvu,
                                           const float* __restrict__ bu,
                                           float* __restrict__ A) {
  __shared__ float vbuf[NV * 8];
  const int tid = threadIdx.x;
  const int t0 = blockIdx.x * 8;
  for (int idx = tid; idx < NV * 8; idx += 256) {
    int j = idx / NV, v = idx - j * NV;
    int t = t0 + j;
    vbuf[v * 8 + j] = (t < TM1) ? visible[(size_t)(t + 1) * NV + v] : 0.f;
  }
  __syncthreads();
  for (int rr = 0; rr < 2; rr++) {
    int r = tid + rr * 256;
    float b0 = bu[r];
    float acc[8];
#pragma unroll
    for (int j = 0; j < 8; j++) acc[j] = b0;
    const float* wr = wvu + (size_t)r * NV;
    for (int v = 0; v < NV; v++) {
      float wv = wr[v];
#pragma unroll
      for (int j = 0; j < 8; j++) acc[j] = fmaf(wv, vbuf[v * 8 + j], acc[j]);
    }
#pragma unroll
    for (int j = 0; j < 8; j++) {
      int t = t0 + j;
      if (t < TM1) A[(size_t)t * NR + r] = acc[j];
    }
  }
}

// ---------------- K_R: sums of squares for the two Frobenius norms ----------------
__global__ __launch_bounds__(256) void k_r(const float* __restrict__ wuv,
                                           const float* __restrict__ wuh,
                                           float* __restrict__ sc) {
  size_t stride = (size_t)gridDim.x * 256;
  size_t gid = (size_t)blockIdx.x * 256 + threadIdx.x;
  float s1 = 0.f, s2 = 0.f;
  for (size_t i = gid; i < (size_t)NV * NR; i += stride) { float x = wuv[i]; s1 = fmaf(x, x, s1); }
  for (size_t i = gid; i < (size_t)NH * NR; i += stride) { float x = wuh[i]; s2 = fmaf(x, x, s2); }
  for (int off = 32; off > 0; off >>= 1) {
    s1 += __shfl_down(s1, off, 64);
    s2 += __shfl_down(s2, off, 64);
  }
  if ((threadIdx.x & 63) == 0) {
    atomicAdd(&sc[1], s1);
    atomicAdd(&sc[2], s2);
  }
}

// ---------------- K_U v14: pure-v9 producers + dedicated REPUBLISHER block ---------
// 256 blocks x 512 thr, 1 block/CU (84KB LDS pad). The co-XCD claim now takes
// FIVE blocks: slots 0..3 run the EXACT verified v9 recurrence (no publish, no
// flags -- standalone pace); slot 4 is a republisher whose 8 waves poll U rows
// via the proven sc0 rolling poll (same XCD-L2), relay them to the A slots
// with sys-scope stores, and raise the 8 per-line flags every 32 rows after a
// vmcnt(0) drain (same release semantics as before, but entirely OFF the
// producers' critical path). Causality: republisher writes A[t-1] only after
// observing U[t], which the producer stores strictly after its own A[t-1]
// read drained. Consumers (dynamic 8-row-chunk queue) unchanged from v13.
__global__ __launch_bounds__(512, 2) void k_u14(const float* __restrict__ wuu,
                                                float* A,           // A in, published U out
                                                const float* __restrict__ u0,
                                                float* __restrict__ U,
                                                unsigned* __restrict__ ub,
                                                const float* __restrict__ visible,
                                                const float* __restrict__ w,
                                                const float* __restrict__ rand_h,
                                                const float* __restrict__ rand_v,
                                                const float* __restrict__ wuh,
                                                const float* __restrict__ wuv,
                                                const float* __restrict__ bh,
                                                const float* __restrict__ bv,
                                                float* __restrict__ out) {
  __shared__ int s_slot;
  __shared__ int s_fast;
  __shared__ int s_cid;
  __shared__ float red2[256];
  __shared__ __align__(16) union {
    struct { float u_buf[NR]; float partials[2][1024]; } p;                      // producer
    struct { float bht[8 * NH]; float bvt[8 * NV]; float uT[NR * 20]; } b;       // bh phase
    struct { float bht[8 * NH]; float bvt[8 * NV]; float vlds[NV * 10]; float hlds[NH * 20]; } g; // gibbs
    float occupancy_pad[21000];  // 84000 B -> 1 block/CU
  } sh;
  const int tid = threadIdx.x;
  unsigned* claimc = ub + 8;
  unsigned* winner = ub + 16;
  unsigned* hs     = ub + 17;
  unsigned* vd     = ub + 33;
  unsigned* flags  = ub + 64;   // flag i at flags[i*16] -- one 64B line each

  // ---- claim 5 co-XCD blocks (4 producers + 1 republisher) ----
  if (tid == 0) {
    unsigned xcd;
    asm volatile("s_getreg_b32 %0, hwreg(HW_REG_XCC_ID, 0, 4)" : "=s"(xcd));
    xcd &= 7u;
    unsigned c = atomicAdd(&claimc[xcd], 1u);
    int slot = -1;
    if (c < 5u) {
      if (c == 3u) atomicCAS(winner, 0xFFFFFFFFu, xcd);
      unsigned wnr;
      do { wnr = agent_load_u32(winner); } while (wnr == 0xFFFFFFFFu);
      if (wnr == xcd) slot = (int)c;   // 0..3 producers, 4 republisher
    }
    s_slot = slot;
  }
  __syncthreads();
  const int slot = s_slot;

  if (slot == 4) {
    // =================== REPUBLISHER (co-XCD, off critical path) ===================
    if (tid == 0) {
      int fast = 1;
      for (int o = 0; o < 4; ++o) {
        unsigned v;
        do { v = agent_load_u32(&vd[o]); } while (v == 0xFFFFFFFFu);
        if (v != 1u) fast = 0;
      }
      s_fast = fast;
    }
    __syncthreads();
    const int fast = s_fast;
    const int lane = tid & 63;
    const int kc   = tid >> 6;                 // wave id == column chunk == flag id
    unsigned* aw = (unsigned*)A + kc * 64 + lane;
    const unsigned* up = (const unsigned*)U + kc * 64 + lane;
    for (int t = 1; t <= TM1 - 1; t++) {
      const unsigned* p = up + (size_t)t * NR;
      unsigned wv = fast ? poll_rd_sc0(p) : poll_rd_sys(p);
      store_sys_u32(aw + (size_t)(t - 1) * NR, wv);
      if ((t & 31) == 0) {
        asm volatile("s_waitcnt vmcnt(0)" ::: "memory");
        if (lane == 0) store_sys_u32(&flags[kc * 16], (unsigned)t);
      }
    }
    asm volatile("s_waitcnt vmcnt(0)" ::: "memory");
    if (lane == 0) store_sys_u32(&flags[kc * 16], 4095u);
    return;
  }

  if (slot < 0) {
    // =================== CONSUMER: dynamic 8-row chunk queue ===================
    const int h1 = tid;
    const int tg = tid >> 5, vg = tid & 31;
    const int v0 = vg * 4;
    const bool bact = (vg < 22) && (tg < 8);
    for (;;) {
      if (tid == 0) s_cid = (int)atomicAdd(&ub[56], 1u);
      __syncthreads();
      const int c = s_cid;
      if (c >= NCHUNK) break;
      const int t0c = c * 8;
      const int nt = min(8, TM1 - t0c);
      unsigned need = (unsigned)((t0c + nt - 1 + 31) & ~31);
      if (need > 4064u) need = 4095u;
      if (tid == 0) {
        for (;;) {
          unsigned mn = 0xFFFFFFFFu;
          for (int i = 0; i < 8; i++) { unsigned f = load_sys_u32(&flags[i * 16]); if (f < mn) mn = f; }
          if (mn >= need) break;
          unsigned d = need - mn;                 // distance in steps (~1.05us each)
          if (d >= 30u)      __builtin_amdgcn_s_sleep(255);
          else if (d >= 8u)  __builtin_amdgcn_s_sleep(96);
          else               __builtin_amdgcn_s_sleep(16);
        }
      }
      __syncthreads();
      // ---- stage U rows (vectorized sys loads; row t lives at A slot t-1) ----
      {
        const int tt = tid >> 6, kq = tid & 63;
        const int t = t0c + tt;
        float4 va, vb;
        if (tt < nt) {
          if (t == 0) {
            va = *(const float4*)(u0 + kq * 8);
            vb = *(const float4*)(u0 + kq * 8 + 4);
          } else {
            load_sys_f32x4x2(&A[(size_t)(t - 1) * NR + kq * 8], va, vb);
          }
        } else {
          va.x = va.y = va.z = va.w = 0.f;
          vb.x = vb.y = vb.z = vb.w = 0.f;
        }
        const int k0 = kq * 8;
        sh.b.uT[(k0 + 0) * 20 + tt] = va.x;
        sh.b.uT[(k0 + 1) * 20 + tt] = va.y;
        sh.b.uT[(k0 + 2) * 20 + tt] = va.z;
        sh.b.uT[(k0 + 3) * 20 + tt] = va.w;
        sh.b.uT[(k0 + 4) * 20 + tt] = vb.x;
        sh.b.uT[(k0 + 5) * 20 + tt] = vb.y;
        sh.b.uT[(k0 + 6) * 20 + tt] = vb.z;
        sh.b.uT[(k0 + 7) * 20 + tt] = vb.w;
      }
      __syncthreads();
      // ---- bh_t / bv_t (LDS) + CE ----
      float ce = 0.f;
      {
        const int h = tid;
        const bool hasv = tid < NV;
        float acc1[8], accv[8];
#pragma unroll
        for (int i = 0; i < 8; i++) acc1[i] = accv[i] = 0.f;
        const float* w1p = wuh + (size_t)h * NR;
        const float* wvp = wuv + (size_t)(hasv ? tid : 0) * NR;
        for (int k = 0; k < NR; k++) {
          float u8[8];
#pragma unroll
          for (int q = 0; q < 2; q++) *(float4*)(u8 + 4 * q) = *(const float4*)(sh.b.uT + k * 20 + 4 * q);
          float a = w1p[k];
          float cc = hasv ? wvp[k] : 0.f;
#pragma unroll
          for (int i = 0; i < 8; i++) {
            acc1[i] = fmaf(a, u8[i], acc1[i]);
            accv[i] = fmaf(cc, u8[i], accv[i]);
          }
        }
        float bh1 = bh[h];
#pragma unroll
        for (int i = 0; i < 8; i++)
          if (i < nt) sh.b.bht[i * NH + h] = acc1[i] + bh1;
        if (hasv) {
          float bvv = bv[tid];
          for (int i = 0; i < nt; i++) {
            float x = accv[i] + bvv;
            sh.b.bvt[i * NV + tid] = x;
            float y = sigmoidf_(x);
            float vs = visible[(size_t)(t0c + i + 1) * NV + tid];
            ce += -vs * logf(EPSV + y) - (1.f - vs) * logf(EPSV + 1.f - y);
          }
        }
      }
      __syncthreads();   // uT dead; bht/bvt persist (same offsets in .g)
      // ---- Gibbs init ----
      for (int idx = tid; idx < NV * 8; idx += 512) {
        int j = idx / NV, v = idx - j * NV;
        sh.g.vlds[v * 10 + j] = (j < nt) ? visible[(size_t)(t0c + j + 1) * NV + v] : 0.f;
      }
      __syncthreads();
      for (int k = 0; k < GS; k++) {
        {
          float acc1[8];
#pragma unroll
          for (int i = 0; i < 8; i++) acc1[i] = 0.f;
          const float* w1p = w + (size_t)h1 * NV;
          for (int v = 0; v < NV; v++) {
            float vv[8];
#pragma unroll
            for (int q = 0; q < 2; q++) *(float4*)(vv + 4 * q) = *(const float4*)(sh.g.vlds + v * 10 + 4 * q);
            float a = w1p[v];
#pragma unroll
            for (int i = 0; i < 8; i++) acc1[i] = fmaf(a, vv[i], acc1[i]);
          }
#pragma unroll
          for (int i = 0; i < 8; i++) {
            if (i < nt) {
              size_t t = (size_t)(t0c + i);
              float x1 = acc1[i] + sh.g.bht[i * NH + h1];
              float p1 = sigmoidf_(x1);
              float r1 = rand_h[(t * GS + k) * NH + h1];
              sh.g.hlds[h1 * 20 + i] = (p1 > r1) ? 1.f : 0.f;
            }
          }
        }
        __syncthreads();
        if (bact && tg < nt) {
          float acc[4] = {0.f, 0.f, 0.f, 0.f};
#pragma unroll 4
          for (int h = 0; h < NH; h++) {
            float hv = sh.g.hlds[h * 20 + tg];
            float4 w4 = *(const float4*)(w + (size_t)h * NV + v0);
            acc[0] = fmaf(hv, w4.x, acc[0]);
            acc[1] = fmaf(hv, w4.y, acc[1]);
            acc[2] = fmaf(hv, w4.z, acc[2]);
            acc[3] = fmaf(hv, w4.w, acc[3]);
          }
          size_t t = (size_t)(t0c + tg);
#pragma unroll
          for (int i = 0; i < 4; i++) {
            int v = v0 + i;
            float x = acc[i] + sh.g.bvt[tg * NV + v];
            float p = sigmoidf_(x);
            float r = rand_v[(t * GS + k) * NV + v];
            sh.g.vlds[v * 10 + tg] = (p > r) ? 1.f : 0.f;
          }
        }
        __syncthreads();
      }
      // ---- mse ----
      if (tid < nt) {
        float s = 0.f;
        for (int v = 0; v < NV; v++) {
          float vs = visible[(size_t)(t0c + tid + 1) * NV + v];
          s += fabsf(vs - sh.g.vlds[v * 10 + tid]);
        }
        out[1 + t0c + tid] = s / 88.f;
      }
      // ---- CE tree (per chunk) ----
      if (tid < 256) red2[tid] = ce;
      __syncthreads();
      for (int s = 128; s > 0; s >>= 1) {
        if (tid < s) red2[tid] += red2[tid + s];
        __syncthreads();
      }
      if (tid == 0) atomicAdd((float*)ub, red2[0]);
      __syncthreads();  // LDS reuse by next chunk
    }
    return;
  }

  // =================== PRODUCER PATH (exact verified v9) ===================
  if (tid == 0) {
    int fast = 1;
    for (int round = 0; round < 4 && fast; ++round) {
      unsigned* hw = hs + round * 4;
      store_sc0((float*)&hw[slot], 0.0f);
      for (int o = 0; o < 4; ++o) {
        if (o == slot) continue;
        int ok = 0;
        for (int it = 0; it < 300; ++it) {
          if (load_sc0(&hw[o]) != 0xFFFFFFFFu) { ok = 1; break; }
        }
        if (!ok) fast = 0;
      }
    }
    __hip_atomic_store(&vd[slot], (unsigned)(fast ? 1 : 0),
                       __ATOMIC_RELAXED, __HIP_MEMORY_SCOPE_AGENT);
    for (int o = 0; o < 4; ++o) {
      unsigned v;
      do { v = agent_load_u32(&vd[o]); } while (v == 0xFFFFFFFFu);
      if (v != 1u) fast = 0;
    }
    s_fast = fast;
  }
  __syncthreads();
  const int fast = s_fast;

  const int lane = tid & 63;
  const int kc   = tid >> 6;                  // wave id == k-chunk 0..7
  const int r0   = slot * 128;
  const bool is_red = (kc >> 1) == slot;      // own chunks 2*slot, 2*slot+1
  const int s_row = ((kc & 1) << 6) + lane;   // reduce wave's row 0..127
  float* ubw = sh.p.u_buf + kc * 64;

  float WregA[64], WregB[64];
  {
    const float* wra = wuu + (size_t)(r0 + lane) * NR + kc * 64;
    const float* wrb = wuu + (size_t)(r0 + lane + 64) * NR + kc * 64;
#pragma unroll
    for (int i = 0; i < 16; i++) {
      ((float4*)WregA)[i] = ((const float4*)wra)[i];
      ((float4*)WregB)[i] = ((const float4*)wrb)[i];
    }
  }
#pragma unroll
  for (int i = 0; i < 64; i++) asm volatile("" : "+v"(WregA[i]));
#pragma unroll
  for (int i = 0; i < 64; i++) asm volatile("" : "+v"(WregB[i]));

  float val = 0.f, a_cur = 0.f;
  if (is_red) {
    agent_store_f32(&U[r0 + s_row], u0[r0 + s_row]);  // row 0 (never polled)
    a_cur = A[r0 + s_row];                            // A row 0, for step t=1
  }
  unsigned ps1 = 0, ps2 = 0, ps3 = 0, ps4 = 0;
  __syncthreads();

#define KU_STEP(T_, UVAL_) do {                                                \
    ubw[lane] = (UVAL_);                                                       \
    float acc0 = 0.f, acc1 = 0.f;                                              \
    _Pragma("unroll")                                                          \
    for (int i = 0; i < 64; i += 4) {                                          \
      float4 uv = *(const float4*)(ubw + i);                                   \
      acc0 = fmaf(WregA[i],     uv.x, acc0);                                   \
      acc1 = fmaf(WregB[i],     uv.x, acc1);                                   \
      acc0 = fmaf(WregA[i + 1], uv.y, acc0);                                   \
      acc1 = fmaf(WregB[i + 1], uv.y, acc1);                                   \
      acc0 = fmaf(WregA[i + 2], uv.z, acc0);                                   \
      acc1 = fmaf(WregB[i + 2], uv.z, acc1);                                   \
      acc0 = fmaf(WregA[i + 3], uv.w, acc0);                                   \
      acc1 = fmaf(WregB[i + 3], uv.w, acc1);                                   \
    }                                                                          \
    float* pb = sh.p.partials[(T_) & 1];                                       \
    pb[kc * 128 + lane] = acc0;                                                \
    pb[kc * 128 + lane + 64] = acc1;                                           \
    __syncthreads();                                                           \
    if (is_red) {                                                              \
      float s = a_cur;                                                         \
      _Pragma("unroll")                                                        \
      for (int kk = 0; kk < 8; kk++) s += pb[kk * 128 + s_row];                \
      val = tanhf(s);                                                          \
      if (fast) store_sc0(&U[(size_t)(T_) * NR + r0 + s_row], val);            \
      else      agent_store_f32(&U[(size_t)(T_) * NR + r0 + s_row], val);      \
      a_cur = A[(size_t)(T_) * NR + r0 + s_row];  /* prefetch A[t] for t+1 */  \
    }                                                                          \
  } while (0)

  KU_STEP(1, u0[kc * 64 + lane]);
  for (int t = 2; t <= TM1 - 1; t++) {
    float u_val;
    if (is_red) {
      u_val = val;
    } else {
      const unsigned* p = (const unsigned*)(U + (size_t)(t - 1) * NR) + kc * 64 + lane;
      unsigned wv = fast ? poll_nd_sc0(p, ps1, ps2, ps3, ps4)
                         : poll_nd_sys(p, ps1, ps2, ps3, ps4);
      u_val = __uint_as_float(wv);
    }
    KU_STEP(t, u_val);
  }
#undef KU_STEP
}

// ---------------- K_F: finalize scalars ----------------
__global__ void k_f(const float* __restrict__ sc, float* __restrict__ out) {
  float reg = 0.2f * (sqrtf(sc[1]) + sqrtf(sc[2]));
  out[0] = sc[0] / 4096.f + reg;
  out[4096] = reg;
}

extern "C" void kernel_launch(void* const* d_in, const int* in_sizes, int n_in,
                              void* d_out, int out_size, void* d_ws, size_t ws_size,
                              hipStream_t stream) {
  const float* visible = (const float*)d_in[0];
  const float* rand_h  = (const float*)d_in[1];
  const float* rand_v  = (const float*)d_in[2];
  const float* w       = (const float*)d_in[3];
  const float* wuu     = (const float*)d_in[4];
  const float* wuv     = (const float*)d_in[5];
  const float* wuh     = (const float*)d_in[6];
  const float* wvu     = (const float*)d_in[7];
  const float* bv      = (const float*)d_in[8];
  const float* bh      = (const float*)d_in[9];
  const float* bu      = (const float*)d_in[10];
  const float* u0      = (const float*)d_in[11];
  float* out = (float*)d_out;
  float* ws = (float*)d_ws;

  float* Uarr = ws + U_OFF;
  float* Aarr = ws + AB_OFF;  // A; rows become published-U slots after consumption
  float* sc   = ws + SC_OFF;
  unsigned* ub = (unsigned*)sc;

  // poison U (poll-on-data); zero accumulators + claim counts;
  // poison winner/handshake/verdict words; zero queue counter + spread flags
  hipMemsetAsync(Uarr, 0xFF, (size_t)TM1 * NR * sizeof(float), stream);
  hipMemsetAsync(sc, 0, 64, stream);
  hipMemsetAsync((char*)sc + 64, 0xFF, 96, stream);
  hipMemsetAsync((char*)sc + 160, 0, 608, stream);  // bytes 160..768: counter + flags

  k_a<<<512, 256, 0, stream>>>(visible, wvu, bu, Aarr);
  k_r<<<64, 256, 0, stream>>>(wuv, wuh, sc);
  k_u14<<<256, 512, 0, stream>>>(wuu, Aarr, u0, Uarr, ub,
                                 visible, w, rand_h, rand_v,
                                 wuh, wuv, bh, bv, out);
  k_f<<<1, 1, 0, stream>>>(sc, out);
}

// Round 12
// 5144.810 us; speedup vs baseline: 1.0332x; 1.0332x over previous
//
#include <hip/hip_runtime.h>
#include <cstdint>
#include <cstddef>

#define T4096 4096
#define TM1 4095
#define NV 88
#define NH 512
#define NR 512
#define GS 20
#define EPSV 1e-6f
#define NCHUNK 512   // 8-row consumer chunks

// ws float offsets
#define U_OFF 0                         // 4095*512 floats
#define AB_OFF 2096640                  // A; rows re-used as published-U slots
#define SC_OFF 4553640                  // scalars + sync area
// u32 layout at sc: [0..2] accumulators, [8..15] xcd claim counts,
// [16] winner, [17..32] handshake words, [33..36] verdicts,
// [56] chunk queue counter (own line),
// [64 + i*16] progress flags, ONE PER 64B LINE (i = 0..7)

__device__ __forceinline__ unsigned int agent_load_u32(const unsigned int* p) {
  return __hip_atomic_load(p, __ATOMIC_RELAXED, __HIP_MEMORY_SCOPE_AGENT);
}
__device__ __forceinline__ void agent_store_f32(float* p, float v) {
  __hip_atomic_store(p, v, __ATOMIC_RELAXED, __HIP_MEMORY_SCOPE_AGENT);
}
__device__ __forceinline__ float sigmoidf_(float x) {
  return 1.0f / (1.0f + expf(-x));
}

// sc0 = SE-scope: bypasses L1, served by the XCD-shared L2.
__device__ __forceinline__ void store_sc0(float* p, float v) {
  asm volatile("global_store_dword %0, %1, off sc0" :: "v"(p), "v"(v) : "memory");
}
__device__ __forceinline__ unsigned load_sc0(const unsigned* p) {
  unsigned r;
  asm volatile("global_load_dword %0, %1, off sc0\n\ts_waitcnt vmcnt(0)"
               : "=v"(r) : "v"(p) : "memory");
  return r;
}
// System-scope (sc0 sc1): LLC-visible to all XCDs.
__device__ __forceinline__ void store_sys_f32(float* p, float v) {
  asm volatile("global_store_dword %0, %1, off sc0 sc1" :: "v"(p), "v"(v) : "memory");
}
__device__ __forceinline__ void store_sys_u32(unsigned* p, unsigned v) {
  asm volatile("global_store_dword %0, %1, off sc0 sc1" :: "v"(p), "v"(v) : "memory");
}
__device__ __forceinline__ unsigned load_sys_u32(const unsigned* p) {
  unsigned r;
  asm volatile("global_load_dword %0, %1, off sc0 sc1\n\ts_waitcnt vmcnt(0)"
               : "=v"(r) : "v"(p) : "memory");
  return r;
}
// Paired 16B sys loads, single drain: staging reads 8 floats per thread.
__device__ __forceinline__ void load_sys_f32x4x2(const float* p, float4& a, float4& b) {
  asm volatile("global_load_dwordx4 %0, %2, off sc0 sc1\n\t"
               "global_load_dwordx4 %1, %3, off sc0 sc1\n\t"
               "s_waitcnt vmcnt(0)"
               : "=&v"(a), "=&v"(b)
               : "v"(p), "v"(p + 4) : "memory");
}

// No-drain rolling poll (R4-verified): 4 loop-persistent in-flight loads,
// vmcnt(3) waits only the oldest; exit on discovery leaves 3 in flight,
// drained for free at the next barrier behind the matvec.
__device__ __forceinline__ unsigned poll_nd_sc0(const unsigned* p,
                                                unsigned& s1, unsigned& s2,
                                                unsigned& s3, unsigned& s4) {
  unsigned rA;
  asm volatile(
    "v_mov_b32 %0, -1\n\t"
    "global_load_dword %1, %5, off sc0\n\t"
    "global_load_dword %2, %5, off sc0\n\t"
    "global_load_dword %3, %5, off sc0\n\t"
    "global_load_dword %4, %5, off sc0\n\t"
    "Lr%=:\n\t"
    "s_waitcnt vmcnt(3)\n\t"
    "v_cmp_ne_u32 vcc, -1, %1\n\t"
    "v_cndmask_b32 %0, %0, %1, vcc\n\t"
    "v_cmp_eq_u32 vcc, -1, %0\n\t"
    "s_cbranch_vccz Le%=\n\t"
    "global_load_dword %1, %5, off sc0\n\t"
    "s_waitcnt vmcnt(3)\n\t"
    "v_cmp_ne_u32 vcc, -1, %2\n\t"
    "v_cndmask_b32 %0, %0, %2, vcc\n\t"
    "v_cmp_eq_u32 vcc, -1, %0\n\t"
    "s_cbranch_vccz Le%=\n\t"
    "global_load_dword %2, %5, off sc0\n\t"
    "s_waitcnt vmcnt(3)\n\t"
    "v_cmp_ne_u32 vcc, -1, %3\n\t"
    "v_cndmask_b32 %0, %0, %3, vcc\n\t"
    "v_cmp_eq_u32 vcc, -1, %0\n\t"
    "s_cbranch_vccz Le%=\n\t"
    "global_load_dword %3, %5, off sc0\n\t"
    "s_waitcnt vmcnt(3)\n\t"
    "v_cmp_ne_u32 vcc, -1, %4\n\t"
    "v_cndmask_b32 %0, %0, %4, vcc\n\t"
    "v_cmp_eq_u32 vcc, -1, %0\n\t"
    "s_cbranch_vccz Le%=\n\t"
    "global_load_dword %4, %5, off sc0\n\t"
    "s_branch Lr%=\n\t"
    "Le%=:\n\t"
    : "=&v"(rA), "+v"(s1), "+v"(s2), "+v"(s3), "+v"(s4)
    : "v"(p) : "vcc", "memory");
  return rA;
}
__device__ __forceinline__ unsigned poll_nd_sys(const unsigned* p,
                                                unsigned& s1, unsigned& s2,
                                                unsigned& s3, unsigned& s4) {
  unsigned rA;
  asm volatile(
    "v_mov_b32 %0, -1\n\t"
    "global_load_dword %1, %5, off sc0 sc1\n\t"
    "global_load_dword %2, %5, off sc0 sc1\n\t"
    "global_load_dword %3, %5, off sc0 sc1\n\t"
    "global_load_dword %4, %5, off sc0 sc1\n\t"
    "Lq%=:\n\t"
    "s_waitcnt vmcnt(3)\n\t"
    "v_cmp_ne_u32 vcc, -1, %1\n\t"
    "v_cndmask_b32 %0, %0, %1, vcc\n\t"
    "v_cmp_eq_u32 vcc, -1, %0\n\t"
    "s_cbranch_vccz Lf%=\n\t"
    "global_load_dword %1, %5, off sc0 sc1\n\t"
    "s_waitcnt vmcnt(3)\n\t"
    "v_cmp_ne_u32 vcc, -1, %2\n\t"
    "v_cndmask_b32 %0, %0, %2, vcc\n\t"
    "v_cmp_eq_u32 vcc, -1, %0\n\t"
    "s_cbranch_vccz Lf%=\n\t"
    "global_load_dword %2, %5, off sc0 sc1\n\t"
    "s_waitcnt vmcnt(3)\n\t"
    "v_cmp_ne_u32 vcc, -1, %3\n\t"
    "v_cndmask_b32 %0, %0, %3, vcc\n\t"
    "v_cmp_eq_u32 vcc, -1, %0\n\t"
    "s_cbranch_vccz Lf%=\n\t"
    "global_load_dword %3, %5, off sc0 sc1\n\t"
    "s_waitcnt vmcnt(3)\n\t"
    "v_cmp_ne_u32 vcc, -1, %4\n\t"
    "v_cndmask_b32 %0, %0, %4, vcc\n\t"
    "v_cmp_eq_u32 vcc, -1, %0\n\t"
    "s_cbranch_vccz Lf%=\n\t"
    "global_load_dword %4, %5, off sc0 sc1\n\t"
    "s_branch Lq%=\n\t"
    "Lf%=:\n\t"
    : "=&v"(rA), "+v"(s1), "+v"(s2), "+v"(s3), "+v"(s4)
    : "v"(p) : "vcc", "memory");
  return rA;
}

// ---------------- K_A: A[t][r] = sum_v wvu[r][v]*v_seq[t][v] + bu[r] ----------------
__global__ __launch_bounds__(256) void k_a(const float* __restrict__ visible,
                                           const float* __restrict__ wvu,
                                           const float* __restrict__ bu,
                                           float* __restrict__ A) {
  __shared__ float vbuf[NV * 8];
  const int tid = threadIdx.x;
  const int t0 = blockIdx.x * 8;
  for (int idx = tid; idx < NV * 8; idx += 256) {
    int j = idx / NV, v = idx - j * NV;
    int t = t0 + j;
    vbuf[v * 8 + j] = (t < TM1) ? visible[(size_t)(t + 1) * NV + v] : 0.f;
  }
  __syncthreads();
  for (int rr = 0; rr < 2; rr++) {
    int r = tid + rr * 256;
    float b0 = bu[r];
    float acc[8];
#pragma unroll
    for (int j = 0; j < 8; j++) acc[j] = b0;
    const float* wr = wvu + (size_t)r * NV;
    for (int v = 0; v < NV; v++) {
      float wv = wr[v];
#pragma unroll
      for (int j = 0; j < 8; j++) acc[j] = fmaf(wv, vbuf[v * 8 + j], acc[j]);
    }
#pragma unroll
    for (int j = 0; j < 8; j++) {
      int t = t0 + j;
      if (t < TM1) A[(size_t)t * NR + r] = acc[j];
    }
  }
}

// ---------------- K_R: sums of squares for the two Frobenius norms ----------------
__global__ __launch_bounds__(256) void k_r(const float* __restrict__ wuv,
                                           const float* __restrict__ wuh,
                                           float* __restrict__ sc) {
  size_t stride = (size_t)gridDim.x * 256;
  size_t gid = (size_t)blockIdx.x * 256 + threadIdx.x;
  float s1 = 0.f, s2 = 0.f;
  for (size_t i = gid; i < (size_t)NV * NR; i += stride) { float x = wuv[i]; s1 = fmaf(x, x, s1); }
  for (size_t i = gid; i < (size_t)NH * NR; i += stride) { float x = wuh[i]; s2 = fmaf(x, x, s2); }
  for (int off = 32; off > 0; off >>= 1) {
    s1 += __shfl_down(s1, off, 64);
    s2 += __shfl_down(s2, off, 64);
  }
  if ((threadIdx.x & 63) == 0) {
    atomicAdd(&sc[1], s1);
    atomicAdd(&sc[2], s2);
  }
}

// ---------------- K_U v15: v13 + PRODUCER-XCD ISOLATION ----------------------------
// Identical to the verified v13 (producers publish + per-line flags + tiered
// consumer sleep) except: blocks that land on the WINNER XCD without claiming
// a producer slot EXIT immediately instead of consuming. The producer XCD's
// L2 then serves only the 4 producers' latency-critical sc0 polls/stores --
// no consumer w/rand/A streaming traffic competing for its bandwidth/MSHRs.
// ~27 CUs idle; consumer pool 252 -> ~224 (dynamic queue absorbs it).
__global__ __launch_bounds__(512, 2) void k_u15(const float* __restrict__ wuu,
                                                float* A,           // A in, published U out
                                                const float* __restrict__ u0,
                                                float* __restrict__ U,
                                                unsigned* __restrict__ ub,
                                                const float* __restrict__ visible,
                                                const float* __restrict__ w,
                                                const float* __restrict__ rand_h,
                                                const float* __restrict__ rand_v,
                                                const float* __restrict__ wuh,
                                                const float* __restrict__ wuv,
                                                const float* __restrict__ bh,
                                                const float* __restrict__ bv,
                                                float* __restrict__ out) {
  __shared__ int s_slot;
  __shared__ int s_fast;
  __shared__ int s_cid;
  __shared__ float red2[256];
  __shared__ __align__(16) union {
    struct { float u_buf[NR]; float partials[2][1024]; } p;                      // producer
    struct { float bht[8 * NH]; float bvt[8 * NV]; float uT[NR * 20]; } b;       // bh phase
    struct { float bht[8 * NH]; float bvt[8 * NV]; float vlds[NV * 10]; float hlds[NH * 20]; } g; // gibbs
    float occupancy_pad[21000];  // 84000 B -> 1 block/CU
  } sh;
  const int tid = threadIdx.x;
  unsigned* claimc = ub + 8;
  unsigned* winner = ub + 16;
  unsigned* hs     = ub + 17;
  unsigned* vd     = ub + 33;
  unsigned* flags  = ub + 64;   // flag i at flags[i*16] -- one 64B line each

  // ---- claim 4 co-XCD producers; ALL blocks learn the winner XCD ----
  if (tid == 0) {
    unsigned xcd;
    asm volatile("s_getreg_b32 %0, hwreg(HW_REG_XCC_ID, 0, 4)" : "=s"(xcd));
    xcd &= 7u;
    unsigned c = atomicAdd(&claimc[xcd], 1u);
    if (c == 3u) atomicCAS(winner, 0xFFFFFFFFu, xcd);
    unsigned wnr;
    do { wnr = agent_load_u32(winner); } while (wnr == 0xFFFFFFFFu);
    int slot = -1;
    if (wnr == xcd) slot = (c < 4u) ? (int)c : -2;   // -2: exit, keep producer XCD clean
    s_slot = slot;
  }
  __syncthreads();
  const int slot = s_slot;
  if (slot == -2) return;   // idle CU on the producer XCD -- by design

  if (slot < 0) {
    // =================== CONSUMER: dynamic 8-row chunk queue ===================
    const int h1 = tid;
    const int tg = tid >> 5, vg = tid & 31;
    const int v0 = vg * 4;
    const bool bact = (vg < 22) && (tg < 8);
    for (;;) {
      if (tid == 0) s_cid = (int)atomicAdd(&ub[56], 1u);
      __syncthreads();
      const int c = s_cid;
      if (c >= NCHUNK) break;
      const int t0c = c * 8;
      const int nt = min(8, TM1 - t0c);
      unsigned need = (unsigned)((t0c + nt - 1 + 31) & ~31);
      if (need > 4064u) need = 4095u;
      if (tid == 0) {
        for (;;) {
          unsigned mn = 0xFFFFFFFFu;
          for (int i = 0; i < 8; i++) { unsigned f = load_sys_u32(&flags[i * 16]); if (f < mn) mn = f; }
          if (mn >= need) break;
          unsigned d = need - mn;                 // distance in steps (~1.05us each)
          if (d >= 30u)      __builtin_amdgcn_s_sleep(255);
          else if (d >= 8u)  __builtin_amdgcn_s_sleep(96);
          else               __builtin_amdgcn_s_sleep(16);
        }
      }
      __syncthreads();
      // ---- stage U rows (vectorized sys loads; row t lives at A slot t-1) ----
      {
        const int tt = tid >> 6, kq = tid & 63;
        const int t = t0c + tt;
        float4 va, vb;
        if (tt < nt) {
          if (t == 0) {
            va = *(const float4*)(u0 + kq * 8);
            vb = *(const float4*)(u0 + kq * 8 + 4);
          } else {
            load_sys_f32x4x2(&A[(size_t)(t - 1) * NR + kq * 8], va, vb);
          }
        } else {
          va.x = va.y = va.z = va.w = 0.f;
          vb.x = vb.y = vb.z = vb.w = 0.f;
        }
        const int k0 = kq * 8;
        sh.b.uT[(k0 + 0) * 20 + tt] = va.x;
        sh.b.uT[(k0 + 1) * 20 + tt] = va.y;
        sh.b.uT[(k0 + 2) * 20 + tt] = va.z;
        sh.b.uT[(k0 + 3) * 20 + tt] = va.w;
        sh.b.uT[(k0 + 4) * 20 + tt] = vb.x;
        sh.b.uT[(k0 + 5) * 20 + tt] = vb.y;
        sh.b.uT[(k0 + 6) * 20 + tt] = vb.z;
        sh.b.uT[(k0 + 7) * 20 + tt] = vb.w;
      }
      __syncthreads();
      // ---- bh_t / bv_t (LDS) + CE ----
      float ce = 0.f;
      {
        const int h = tid;
        const bool hasv = tid < NV;
        float acc1[8], accv[8];
#pragma unroll
        for (int i = 0; i < 8; i++) acc1[i] = accv[i] = 0.f;
        const float* w1p = wuh + (size_t)h * NR;
        const float* wvp = wuv + (size_t)(hasv ? tid : 0) * NR;
        for (int k = 0; k < NR; k++) {
          float u8[8];
#pragma unroll
          for (int q = 0; q < 2; q++) *(float4*)(u8 + 4 * q) = *(const float4*)(sh.b.uT + k * 20 + 4 * q);
          float a = w1p[k];
          float cc = hasv ? wvp[k] : 0.f;
#pragma unroll
          for (int i = 0; i < 8; i++) {
            acc1[i] = fmaf(a, u8[i], acc1[i]);
            accv[i] = fmaf(cc, u8[i], accv[i]);
          }
        }
        float bh1 = bh[h];
#pragma unroll
        for (int i = 0; i < 8; i++)
          if (i < nt) sh.b.bht[i * NH + h] = acc1[i] + bh1;
        if (hasv) {
          float bvv = bv[tid];
          for (int i = 0; i < nt; i++) {
            float x = accv[i] + bvv;
            sh.b.bvt[i * NV + tid] = x;
            float y = sigmoidf_(x);
            float vs = visible[(size_t)(t0c + i + 1) * NV + tid];
            ce += -vs * logf(EPSV + y) - (1.f - vs) * logf(EPSV + 1.f - y);
          }
        }
      }
      __syncthreads();   // uT dead; bht/bvt persist (same offsets in .g)
      // ---- Gibbs init ----
      for (int idx = tid; idx < NV * 8; idx += 512) {
        int j = idx / NV, v = idx - j * NV;
        sh.g.vlds[v * 10 + j] = (j < nt) ? visible[(size_t)(t0c + j + 1) * NV + v] : 0.f;
      }
      __syncthreads();
      for (int k = 0; k < GS; k++) {
        {
          float acc1[8];
#pragma unroll
          for (int i = 0; i < 8; i++) acc1[i] = 0.f;
          const float* w1p = w + (size_t)h1 * NV;
          for (int v = 0; v < NV; v++) {
            float vv[8];
#pragma unroll
            for (int q = 0; q < 2; q++) *(float4*)(vv + 4 * q) = *(const float4*)(sh.g.vlds + v * 10 + 4 * q);
            float a = w1p[v];
#pragma unroll
            for (int i = 0; i < 8; i++) acc1[i] = fmaf(a, vv[i], acc1[i]);
          }
#pragma unroll
          for (int i = 0; i < 8; i++) {
            if (i < nt) {
              size_t t = (size_t)(t0c + i);
              float x1 = acc1[i] + sh.g.bht[i * NH + h1];
              float p1 = sigmoidf_(x1);
              float r1 = rand_h[(t * GS + k) * NH + h1];
              sh.g.hlds[h1 * 20 + i] = (p1 > r1) ? 1.f : 0.f;
            }
          }
        }
        __syncthreads();
        if (bact && tg < nt) {
          float acc[4] = {0.f, 0.f, 0.f, 0.f};
#pragma unroll 4
          for (int h = 0; h < NH; h++) {
            float hv = sh.g.hlds[h * 20 + tg];
            float4 w4 = *(const float4*)(w + (size_t)h * NV + v0);
            acc[0] = fmaf(hv, w4.x, acc[0]);
            acc[1] = fmaf(hv, w4.y, acc[1]);
            acc[2] = fmaf(hv, w4.z, acc[2]);
            acc[3] = fmaf(hv, w4.w, acc[3]);
          }
          size_t t = (size_t)(t0c + tg);
#pragma unroll
          for (int i = 0; i < 4; i++) {
            int v = v0 + i;
            float x = acc[i] + sh.g.bvt[tg * NV + v];
            float p = sigmoidf_(x);
            float r = rand_v[(t * GS + k) * NV + v];
            sh.g.vlds[v * 10 + tg] = (p > r) ? 1.f : 0.f;
          }
        }
        __syncthreads();
      }
      // ---- mse ----
      if (tid < nt) {
        float s = 0.f;
        for (int v = 0; v < NV; v++) {
          float vs = visible[(size_t)(t0c + tid + 1) * NV + v];
          s += fabsf(vs - sh.g.vlds[v * 10 + tid]);
        }
        out[1 + t0c + tid] = s / 88.f;
      }
      // ---- CE tree (per chunk) ----
      if (tid < 256) red2[tid] = ce;
      __syncthreads();
      for (int s = 128; s > 0; s >>= 1) {
        if (tid < s) red2[tid] += red2[tid + s];
        __syncthreads();
      }
      if (tid == 0) atomicAdd((float*)ub, red2[0]);
      __syncthreads();  // LDS reuse by next chunk
    }
    return;
  }

  // =================== PRODUCER PATH (verified v9 + publish) ===================
  if (tid == 0) {
    int fast = 1;
    for (int round = 0; round < 4 && fast; ++round) {
      unsigned* hw = hs + round * 4;
      store_sc0((float*)&hw[slot], 0.0f);
      for (int o = 0; o < 4; ++o) {
        if (o == slot) continue;
        int ok = 0;
        for (int it = 0; it < 300; ++it) {
          if (load_sc0(&hw[o]) != 0xFFFFFFFFu) { ok = 1; break; }
        }
        if (!ok) fast = 0;
      }
    }
    __hip_atomic_store(&vd[slot], (unsigned)(fast ? 1 : 0),
                       __ATOMIC_RELAXED, __HIP_MEMORY_SCOPE_AGENT);
    for (int o = 0; o < 4; ++o) {
      unsigned v;
      do { v = agent_load_u32(&vd[o]); } while (v == 0xFFFFFFFFu);
      if (v != 1u) fast = 0;
    }
    s_fast = fast;
  }
  __syncthreads();
  const int fast = s_fast;

  const int lane = tid & 63;
  const int kc   = tid >> 6;                  // wave id == k-chunk 0..7
  const int r0   = slot * 128;
  const bool is_red = (kc >> 1) == slot;      // own chunks 2*slot, 2*slot+1
  const int s_row = ((kc & 1) << 6) + lane;   // reduce wave's row 0..127
  const int fid = slot * 2 + (kc & 1);        // progress flag index
  float* ubw = sh.p.u_buf + kc * 64;

  float WregA[64], WregB[64];
  {
    const float* wra = wuu + (size_t)(r0 + lane) * NR + kc * 64;
    const float* wrb = wuu + (size_t)(r0 + lane + 64) * NR + kc * 64;
#pragma unroll
    for (int i = 0; i < 16; i++) {
      ((float4*)WregA)[i] = ((const float4*)wra)[i];
      ((float4*)WregB)[i] = ((const float4*)wrb)[i];
    }
  }
#pragma unroll
  for (int i = 0; i < 64; i++) asm volatile("" : "+v"(WregA[i]));
#pragma unroll
  for (int i = 0; i < 64; i++) asm volatile("" : "+v"(WregB[i]));

  float val = 0.f, a_cur = 0.f;
  if (is_red) {
    agent_store_f32(&U[r0 + s_row], u0[r0 + s_row]);  // row 0 (never polled)
    a_cur = A[r0 + s_row];                            // A row 0, for step t=1
  }
  unsigned ps1 = 0, ps2 = 0, ps3 = 0, ps4 = 0;
  __syncthreads();

#define KU_STEP(T_, UVAL_) do {                                                \
    ubw[lane] = (UVAL_);                                                       \
    float acc0 = 0.f, acc1 = 0.f;                                              \
    _Pragma("unroll")                                                          \
    for (int i = 0; i < 64; i += 4) {                                          \
      float4 uv = *(const float4*)(ubw + i);                                   \
      acc0 = fmaf(WregA[i],     uv.x, acc0);                                   \
      acc1 = fmaf(WregB[i],     uv.x, acc1);                                   \
      acc0 = fmaf(WregA[i + 1], uv.y, acc0);                                   \
      acc1 = fmaf(WregB[i + 1], uv.y, acc1);                                   \
      acc0 = fmaf(WregA[i + 2], uv.z, acc0);                                   \
      acc1 = fmaf(WregB[i + 2], uv.z, acc1);                                   \
      acc0 = fmaf(WregA[i + 3], uv.w, acc0);                                   \
      acc1 = fmaf(WregB[i + 3], uv.w, acc1);                                   \
    }                                                                          \
    float* pb = sh.p.partials[(T_) & 1];                                       \
    pb[kc * 128 + lane] = acc0;                                                \
    pb[kc * 128 + lane + 64] = acc1;                                           \
    __syncthreads();                                                           \
    if (is_red) {                                                              \
      float s = a_cur;                                                         \
      _Pragma("unroll")                                                        \
      for (int kk = 0; kk < 8; kk++) s += pb[kk * 128 + s_row];                \
      val = tanhf(s);                                                          \
      if (fast) store_sc0(&U[(size_t)(T_) * NR + r0 + s_row], val);            \
      else      agent_store_f32(&U[(size_t)(T_) * NR + r0 + s_row], val);      \
      store_sys_f32(&A[(size_t)((T_) - 1) * NR + r0 + s_row], val);            \
      a_cur = A[(size_t)(T_) * NR + r0 + s_row];  /* prefetch A[t] for t+1 */  \
      if (((T_) & 31) == 0) {                                                  \
        asm volatile("s_waitcnt vmcnt(0)" ::: "memory");                       \
        if (lane == 0) store_sys_u32(&flags[fid * 16], (unsigned)(T_));        \
      }                                                                        \
    }                                                                          \
  } while (0)

  KU_STEP(1, u0[kc * 64 + lane]);
  for (int t = 2; t <= TM1 - 1; t++) {
    float u_val;
    if (is_red) {
      u_val = val;
    } else {
      const unsigned* p = (const unsigned*)(U + (size_t)(t - 1) * NR) + kc * 64 + lane;
      unsigned wv = fast ? poll_nd_sc0(p, ps1, ps2, ps3, ps4)
                         : poll_nd_sys(p, ps1, ps2, ps3, ps4);
      u_val = __uint_as_float(wv);
    }
    KU_STEP(t, u_val);
  }
#undef KU_STEP
  // final release flag: everything stored & acked
  if (is_red) {
    asm volatile("s_waitcnt vmcnt(0)" ::: "memory");
    if (lane == 0) store_sys_u32(&flags[fid * 16], 4095u);
  }
}

// ---------------- K_F: finalize scalars ----------------
__global__ void k_f(const float* __restrict__ sc, float* __restrict__ out) {
  float reg = 0.2f * (sqrtf(sc[1]) + sqrtf(sc[2]));
  out[0] = sc[0] / 4096.f + reg;
  out[4096] = reg;
}

extern "C" void kernel_launch(void* const* d_in, const int* in_sizes, int n_in,
                              void* d_out, int out_size, void* d_ws, size_t ws_size,
                              hipStream_t stream) {
  const float* visible = (const float*)d_in[0];
  const float* rand_h  = (const float*)d_in[1];
  const float* rand_v  = (const float*)d_in[2];
  const float* w       = (const float*)d_in[3];
  const float* wuu     = (const float*)d_in[4];
  const float* wuv     = (const float*)d_in[5];
  const float* wuh     = (const float*)d_in[6];
  const float* wvu     = (const float*)d_in[7];
  const float* bv      = (const float*)d_in[8];
  const float* bh      = (const float*)d_in[9];
  const float* bu      = (const float*)d_in[10];
  const float* u0      = (const float*)d_in[11];
  float* out = (float*)d_out;
  float* ws = (float*)d_ws;

  float* Uarr = ws + U_OFF;
  float* Aarr = ws + AB_OFF;  // A; rows become published-U slots after consumption
  float* sc   = ws + SC_OFF;
  unsigned* ub = (unsigned*)sc;

  // poison U (poll-on-data); zero accumulators + claim counts;
  // poison winner/handshake/verdict words; zero queue counter + spread flags
  hipMemsetAsync(Uarr, 0xFF, (size_t)TM1 * NR * sizeof(float), stream);
  hipMemsetAsync(sc, 0, 64, stream);
  hipMemsetAsync((char*)sc + 64, 0xFF, 96, stream);
  hipMemsetAsync((char*)sc + 160, 0, 608, stream);  // bytes 160..768: counter + flags

  k_a<<<512, 256, 0, stream>>>(visible, wvu, bu, Aarr);
  k_r<<<64, 256, 0, stream>>>(wuv, wuh, sc);
  k_u15<<<256, 512, 0, stream>>>(wuu, Aarr, u0, Uarr, ub,
                                 visible, w, rand_h, rand_v,
                                 wuh, wuv, bh, bv, out);
  k_f<<<1, 1, 0, stream>>>(sc, out);
}